// Round 1
// baseline (4454.602 us; speedup 1.0000x reference)
//
#include <hip/hip_runtime.h>
#include <cstdint>
#include <cstddef>

static constexpr int T_STEPS = 2048;
static constexpr int BATCH   = 32;
static constexpr int DIM     = 256;
static constexpr int NCOL    = 512;
static constexpr size_t M_ROWS = (size_t)T_STEPS * BATCH;   // 65536

typedef _Float16 f16x4 __attribute__((ext_vector_type(4)));
typedef _Float16 f16x8 __attribute__((ext_vector_type(8)));
typedef float    f32x4 __attribute__((ext_vector_type(4)));
struct alignas(8) H4 { _Float16 x, y, z, w; };

// ---- workspace layout (bytes) ----
static constexpr size_t XW_OFF   = 0;                           // XW f16 [65536][512] (bias folded) = 64 MB
static constexpr size_t A_OFF    = M_ROWS * NCOL * 2;           // Abuf f16 [65536][256] = 32 MB
static constexpr size_t BLOB_OFF = A_OFF + M_ROWS * DIM * 2;    // 4 blobs x 256 KB
static constexpr size_t BLOB_ELT = (size_t)DIM * NCOL;          // 131072 f16 per blob

// ---------------- prep: f32 -> f16 convert (input) ----------------
__global__ void cvt_f32_to_f16(const float* __restrict__ src, _Float16* __restrict__ dst, int n4) {
  int i = blockIdx.x * blockDim.x + threadIdx.x;
  if (i >= n4) return;
  float4 v = ((const float4*)src)[i];
  H4 o; o.x = (_Float16)v.x; o.y = (_Float16)v.y; o.z = (_Float16)v.z; o.w = (_Float16)v.w;
  ((H4*)dst)[i] = o;
}

// ---------------- prep: W -> MFMA B-fragment blobs (cols 0:512 of [256][768]) ----
// blob[tn][kc][lane][j] = W[kc*32 + (lane>>4)*8 + j][tn*16 + (lane&15)]
__global__ void prep_blobs4(const float* __restrict__ w0, const float* __restrict__ w1,
                            const float* __restrict__ w2, const float* __restrict__ w3,
                            _Float16* __restrict__ blobs) {
  int gid = blockIdx.x * blockDim.x + threadIdx.x;   // < 4*131072
  int mat = gid >> 17;
  int rem = gid & 131071;
  int k = rem >> 9;        // 0..255
  int n = rem & 511;       // 0..511
  const float* src = (mat == 0) ? w0 : (mat == 1) ? w1 : (mat == 2) ? w2 : w3;
  float v = src[k * 768 + n];
  int kc = k >> 5, q = (k >> 3) & 3, j = k & 7, tn = n >> 4;
  int lane = (n & 15) + 16 * q;
  blobs[(size_t)mat * BLOB_ELT + ((size_t)(tn * 8 + kc) * 64 + lane) * 8 + j] = (_Float16)v;
}

// ---------------- GEMM: XW = A[65536,256] @ B[256,512] + bias, row-major f16 ----
__global__ __launch_bounds__(256) void gemm_xw(const _Float16* __restrict__ A,
                                               const _Float16* __restrict__ blob,
                                               const float* __restrict__ bias,
                                               _Float16* __restrict__ XW) {
  int lane = threadIdx.x & 63;
  int wave = threadIdx.x >> 6;
  int wid  = blockIdx.x * 4 + wave;       // 0..8191
  int mbase = (wid >> 1) * 16;
  int nhalf = wid & 1;
  int q = lane >> 4, n15 = lane & 15;

  f32x4 acc[16];
#pragma unroll
  for (int i = 0; i < 16; i++) acc[i] = (f32x4){0.f, 0.f, 0.f, 0.f};

  const _Float16* Arow = A + (size_t)(mbase + n15) * DIM + q * 8;
#pragma unroll
  for (int kc = 0; kc < 8; kc++) {
    f16x8 af = *(const f16x8*)(Arow + kc * 32);
#pragma unroll
    for (int nt = 0; nt < 16; nt++) {
      const _Float16* bp = blob + ((size_t)((nhalf * 16 + nt) * 8 + kc) * 64 + lane) * 8;
      f16x8 bf = *(const f16x8*)bp;
      acc[nt] = __builtin_amdgcn_mfma_f32_16x16x32_f16(af, bf, acc[nt], 0, 0, 0);
    }
  }
#pragma unroll
  for (int nt = 0; nt < 16; nt++) {
    int col = nhalf * 256 + nt * 16 + n15;
    float bv = bias[col];
#pragma unroll
    for (int r = 0; r < 4; r++) {
      int m = mbase + q * 4 + r;
      XW[(size_t)m * NCOL + col] = (_Float16)(acc[nt][r] + bv);
    }
  }
}

// ---------------- recurrence (batch-per-WG MFMA GEMV) ----------------
__device__ __forceinline__ int read_len(const void* p, int b) {
  const long long* q = (const long long*)p;
  bool ok64 = true;
  for (int i = 0; i < 32; i++) { long long v = q[i]; if (v < 0 || v > 2048) ok64 = false; }
  return ok64 ? (int)q[b] : ((const int*)p)[b];
}

// 32 WGs (one batch each), 512 threads = 8 waves, 2 waves/SIMD.
// Wave w owns N-tiles {2w, 2w+1} (h-gate cols 32w..32w+31) and {16+2w, 17+2w}
// (matching t-gate cols +256). M=1 GEMV via 16x16x32 MFMA: every lane's
// A-frag is h[kc*32 + q*8 .. +7], so ALL 16 output rows are duplicates ->
// every lane/reg holds a valid pre[col]; no exchange, no masking in compute.
// h round-trips through a 256-elem f16 LDS buffer (ping-pong, ONE barrier).
//
// KEY CHANGE vs previous version: per-step sync is a raw
//   s_waitcnt lgkmcnt(0); s_barrier
// (only the LDS h-publish is ordered), NOT __syncthreads() (which drains
// vmcnt(0) and serializes the xw prefetch loads + out stores into the
// 2048-step critical path). xw prefetch deepened to 2 steps; x addend is
// folded into the MFMA C-in operand (all rows duplicate, so C={x,x,x,x}).
template <int LAYER>
__global__ __launch_bounds__(512, 2) void recur(const _Float16* __restrict__ xw,
                                                const _Float16* __restrict__ bblob,
                                                const void* __restrict__ lenp,
                                                _Float16* __restrict__ out0,
                                                float* __restrict__ out1,
                                                float* __restrict__ hn) {
  const int b    = blockIdx.x;             // batch
  const int tid  = threadIdx.x;
  const int w    = tid >> 6;               // wave 0..7
  const int lane = tid & 63;
  const int q = lane >> 4, l15 = lane & 15;
  const int len = read_len(lenp, b);

  // Whh B-fragments resident in VGPRs/AGPRs: [pp][kc], h tiles 2w+pp, t tiles 16+2w+pp
  f16x8 Bh[2][8], Bt[2][8];
#pragma unroll
  for (int pp = 0; pp < 2; pp++)
#pragma unroll
    for (int kc = 0; kc < 8; kc++) {
      Bh[pp][kc] = *(const f16x8*)(bblob + ((size_t)((2 * w + pp) * 8 + kc) * 64 + lane) * 8);
      Bt[pp][kc] = *(const f16x8*)(bblob + ((size_t)((16 + 2 * w + pp) * 8 + kc) * 64 + lane) * 8);
    }

  __shared__ __align__(16) _Float16 hbuf[2][DIM];   // ping-pong h (1 KB total)
  if (tid < DIM) hbuf[0][tid] = (_Float16)0.f;
  __syncthreads();

  const int c0 = (2 * w) * 16 + l15;       // h-col of pp=0
  const int c1 = (2 * w + 1) * 16 + l15;   // h-col of pp=1
  const _Float16* xrow = xw + (size_t)b * NCOL;
  const size_t xstride = (size_t)BATCH * NCOL;

  float h0 = 0.f, h1 = 0.f;                // running h for cols c0, c1 (dup across q)
  const float K1 = 1.442695040888963f, K2 = 2.885390081777927f;

  // 2-deep prefetch: set A holds x(t even), set B holds x(t odd)
  float xa0 = (float)xrow[c0],       xa1 = (float)xrow[c1];
  float xa2 = (float)xrow[c0 + 256], xa3 = (float)xrow[c1 + 256];
  const _Float16* x1p = xrow + xstride;
  float xb0 = (float)x1p[c0],       xb1 = (float)x1p[c1];
  float xb2 = (float)x1p[c0 + 256], xb3 = (float)x1p[c1 + 256];

#define RECUR_STEP(T_, P_, X0_, X1_, X2_, X3_)                                   \
  {                                                                              \
    /* fold x into C-in: all 16 MFMA rows are duplicates, so {x,x,x,x} */        \
    f32x4 a0 = {X0_, X0_, X0_, X0_};                                             \
    f32x4 a1 = {X1_, X1_, X1_, X1_};                                             \
    f32x4 a2 = {X2_, X2_, X2_, X2_};                                             \
    f32x4 a3 = {X3_, X3_, X3_, X3_};                                             \
    /* issue prefetch for T_+2 immediately (consumed 2 steps from now) */        \
    if ((T_) + 2 < T_STEPS) {                                                    \
      const _Float16* xn = xrow + (size_t)((T_) + 2) * xstride;                  \
      X0_ = (float)xn[c0];       X1_ = (float)xn[c1];                            \
      X2_ = (float)xn[c0 + 256]; X3_ = (float)xn[c1 + 256];                      \
    }                                                                            \
    const _Float16* hb = &hbuf[P_][q * 8];                                       \
    _Pragma("unroll")                                                            \
    for (int kc = 0; kc < 8; kc++) {                                             \
      f16x8 a = *(const f16x8*)(hb + kc * 32);                                   \
      a0 = __builtin_amdgcn_mfma_f32_16x16x32_f16(a, Bh[0][kc], a0, 0, 0, 0);    \
      a1 = __builtin_amdgcn_mfma_f32_16x16x32_f16(a, Bh[1][kc], a1, 0, 0, 0);    \
      a2 = __builtin_amdgcn_mfma_f32_16x16x32_f16(a, Bt[0][kc], a2, 0, 0, 0);    \
      a3 = __builtin_amdgcn_mfma_f32_16x16x32_f16(a, Bt[1][kc], a3, 0, 0, 0);    \
    }                                                                            \
    const bool live = (T_) < len;                                                \
    {                                                                            \
      float ph = a0[0], pt = a2[0];                                              \
      float phc = fminf(fmaxf(ph, -20.f), 20.f);                                 \
      float e1 = __builtin_amdgcn_exp2f(-K2 * phc);                              \
      float e2 = __builtin_amdgcn_exp2f(-K1 * pt);                               \
      float u1 = 1.f + e1;                                                       \
      float rr = __builtin_amdgcn_rcpf(u1 * (1.f + e2));                         \
      float ttg = (1.f - e1) * rr;                                               \
      float tg  = u1 * rr;                                                       \
      float cg = 0.5f + tg * (0.250905f + tg * (-0.00432f + tg * (-0.015525f))); \
      float s = ttg + h0 * cg;                                                   \
      h0 = live ? s : h0;                                                        \
    }                                                                            \
    {                                                                            \
      float ph = a1[0], pt = a3[0];                                              \
      float phc = fminf(fmaxf(ph, -20.f), 20.f);                                 \
      float e1 = __builtin_amdgcn_exp2f(-K2 * phc);                              \
      float e2 = __builtin_amdgcn_exp2f(-K1 * pt);                               \
      float u1 = 1.f + e1;                                                       \
      float rr = __builtin_amdgcn_rcpf(u1 * (1.f + e2));                         \
      float ttg = (1.f - e1) * rr;                                               \
      float tg  = u1 * rr;                                                       \
      float cg = 0.5f + tg * (0.250905f + tg * (-0.00432f + tg * (-0.015525f))); \
      float s = ttg + h1 * cg;                                                   \
      h1 = live ? s : h1;                                                        \
    }                                                                            \
    _Float16 s0 = (_Float16)h0, s1 = (_Float16)h1;                               \
    if (q == 0) {                           /* 16 lanes publish + store */       \
      hbuf[1 - (P_)][c0] = s0;                                                   \
      hbuf[1 - (P_)][c1] = s1;                                                   \
      size_t o = ((size_t)(T_) * BATCH + b) * DIM;                               \
      if (LAYER == 0) { out0[o + c0] = s0; out0[o + c1] = s1; }                  \
      else            { out1[o + c0] = h0; out1[o + c1] = h1; }                  \
    }                                                                            \
    /* order ONLY the LDS publish; global loads/stores stay in flight */         \
    asm volatile("s_waitcnt lgkmcnt(0)\n\ts_barrier" ::: "memory");              \
  }

  for (int t = 0; t < T_STEPS; t += 2) {
    RECUR_STEP(t,     0, xa0, xa1, xa2, xa3);
    RECUR_STEP(t + 1, 1, xb0, xb1, xb2, xb3);
  }
#undef RECUR_STEP

  if (q == 0) {
    hn[LAYER * (BATCH * DIM) + b * DIM + c0] = h0;
    hn[LAYER * (BATCH * DIM) + b * DIM + c1] = h1;
  }
}

extern "C" void kernel_launch(void* const* d_in, const int* in_sizes, int n_in,
                              void* d_out, int out_size, void* d_ws, size_t ws_size,
                              hipStream_t stream) {
  const float* input_ = (const float*)d_in[0];
  const void*  lenp   = d_in[1];
  const float* Wih0   = (const float*)d_in[2];
  const float* Whh0   = (const float*)d_in[3];
  const float* b0     = (const float*)d_in[4];
  const float* Wih1   = (const float*)d_in[5];
  const float* Whh1   = (const float*)d_in[6];
  const float* b1     = (const float*)d_in[7];
  float* out = (float*)d_out;
  char*  ws  = (char*)d_ws;

  _Float16* XW    = (_Float16*)(ws + XW_OFF);
  _Float16* Abuf  = (_Float16*)(ws + A_OFF);
  _Float16* blobs = (_Float16*)(ws + BLOB_OFF);   // [Wih0, Wih1, Whh0, Whh1]
  float* hn = out + M_ROWS * DIM;                 // d_out tail: h_n [2][32][256]

  cvt_f32_to_f16<<<16384, 256, 0, stream>>>(input_, Abuf, (int)(M_ROWS * DIM / 4));
  prep_blobs4<<<2048, 256, 0, stream>>>(Wih0, Wih1, Whh0, Whh1, blobs);
  gemm_xw<<<2048, 256, 0, stream>>>(Abuf, blobs + 0 * BLOB_ELT, b0, XW);
  recur<0><<<BATCH, 512, 0, stream>>>(XW, blobs + 2 * BLOB_ELT, lenp, Abuf, nullptr, hn);
  gemm_xw<<<2048, 256, 0, stream>>>(Abuf, blobs + 1 * BLOB_ELT, b1, XW);
  recur<1><<<BATCH, 512, 0, stream>>>(XW, blobs + 3 * BLOB_ELT, lenp, nullptr, out, hn);
}

// Round 2
// 3130.712 us; speedup vs baseline: 1.4229x; 1.4229x over previous
//
#include <hip/hip_runtime.h>
#include <cstdint>
#include <cstddef>

static constexpr int T_STEPS = 2048;
static constexpr int BATCH   = 32;
static constexpr int DIM     = 256;
static constexpr int NCOL    = 512;
static constexpr size_t M_ROWS = (size_t)T_STEPS * BATCH;   // 65536

typedef _Float16 f16x4 __attribute__((ext_vector_type(4)));
typedef _Float16 f16x8 __attribute__((ext_vector_type(8)));
typedef float    f32x4 __attribute__((ext_vector_type(4)));
struct alignas(8) H4 { _Float16 x, y, z, w; };

// ---- workspace layout (bytes) ----
static constexpr size_t XW_OFF   = 0;                           // XW f16 [65536][512] (bias folded) = 64 MB
static constexpr size_t A_OFF    = M_ROWS * NCOL * 2;           // Abuf f16 [65536][256] = 32 MB
static constexpr size_t BLOB_OFF = A_OFF + M_ROWS * DIM * 2;    // 4 blobs x 256 KB
static constexpr size_t BLOB_ELT = (size_t)DIM * NCOL;          // 131072 f16 per blob

// ---------------- prep: f32 -> f16 convert (input) ----------------
__global__ void cvt_f32_to_f16(const float* __restrict__ src, _Float16* __restrict__ dst, int n4) {
  int i = blockIdx.x * blockDim.x + threadIdx.x;
  if (i >= n4) return;
  float4 v = ((const float4*)src)[i];
  H4 o; o.x = (_Float16)v.x; o.y = (_Float16)v.y; o.z = (_Float16)v.z; o.w = (_Float16)v.w;
  ((H4*)dst)[i] = o;
}

// ---------------- prep: W -> MFMA B-fragment blobs (cols 0:512 of [256][768]) ----
// blob[tn][kc][lane][j] = W[kc*32 + (lane>>4)*8 + j][tn*16 + (lane&15)]
__global__ void prep_blobs4(const float* __restrict__ w0, const float* __restrict__ w1,
                            const float* __restrict__ w2, const float* __restrict__ w3,
                            _Float16* __restrict__ blobs) {
  int gid = blockIdx.x * blockDim.x + threadIdx.x;   // < 4*131072
  int mat = gid >> 17;
  int rem = gid & 131071;
  int k = rem >> 9;        // 0..255
  int n = rem & 511;       // 0..511
  const float* src = (mat == 0) ? w0 : (mat == 1) ? w1 : (mat == 2) ? w2 : w3;
  float v = src[k * 768 + n];
  int kc = k >> 5, q = (k >> 3) & 3, j = k & 7, tn = n >> 4;
  int lane = (n & 15) + 16 * q;
  blobs[(size_t)mat * BLOB_ELT + ((size_t)(tn * 8 + kc) * 64 + lane) * 8 + j] = (_Float16)v;
}

// ---------------- GEMM: XW = A[65536,256] @ B[256,512] + bias, row-major f16 ----
__global__ __launch_bounds__(256) void gemm_xw(const _Float16* __restrict__ A,
                                               const _Float16* __restrict__ blob,
                                               const float* __restrict__ bias,
                                               _Float16* __restrict__ XW) {
  int lane = threadIdx.x & 63;
  int wave = threadIdx.x >> 6;
  int wid  = blockIdx.x * 4 + wave;       // 0..8191
  int mbase = (wid >> 1) * 16;
  int nhalf = wid & 1;
  int q = lane >> 4, n15 = lane & 15;

  f32x4 acc[16];
#pragma unroll
  for (int i = 0; i < 16; i++) acc[i] = (f32x4){0.f, 0.f, 0.f, 0.f};

  const _Float16* Arow = A + (size_t)(mbase + n15) * DIM + q * 8;
#pragma unroll
  for (int kc = 0; kc < 8; kc++) {
    f16x8 af = *(const f16x8*)(Arow + kc * 32);
#pragma unroll
    for (int nt = 0; nt < 16; nt++) {
      const _Float16* bp = blob + ((size_t)((nhalf * 16 + nt) * 8 + kc) * 64 + lane) * 8;
      f16x8 bf = *(const f16x8*)bp;
      acc[nt] = __builtin_amdgcn_mfma_f32_16x16x32_f16(af, bf, acc[nt], 0, 0, 0);
    }
  }
#pragma unroll
  for (int nt = 0; nt < 16; nt++) {
    int col = nhalf * 256 + nt * 16 + n15;
    float bv = bias[col];
#pragma unroll
    for (int r = 0; r < 4; r++) {
      int m = mbase + q * 4 + r;
      XW[(size_t)m * NCOL + col] = (_Float16)(acc[nt][r] + bv);
    }
  }
}

// ---------------- recurrence (batch-per-WG MFMA GEMV) ----------------
__device__ __forceinline__ int read_len(const void* p, int b) {
  const long long* q = (const long long*)p;
  bool ok64 = true;
  for (int i = 0; i < 32; i++) { long long v = q[i]; if (v < 0 || v > 2048) ok64 = false; }
  return ok64 ? (int)q[b] : ((const int*)p)[b];
}

// async global->LDS staging of one 1KB xw row (64 lanes x 16B)
__device__ __forceinline__ void gload_lds_row(const _Float16* g, _Float16* l) {
  __builtin_amdgcn_global_load_lds(
      (const __attribute__((address_space(1))) void*)g,
      (__attribute__((address_space(3))) void*)l, 16, 0, 0);
}

// 32 WGs (one batch each), 512 threads = 8 waves, 2 waves/SIMD.
// Wave w owns N-tiles {2w, 2w+1} (h-gate cols 32w..32w+31) and {16+2w, 17+2w}
// (matching t-gate cols +256). M=1 GEMV via 16x16x32 MFMA: every lane's
// A-frag is h[kc*32 + q*8 .. +7], so ALL 16 output rows are duplicates ->
// every lane/reg holds a valid pre[col]; no exchange, no masking in compute.
//
// Structure vs 1713us baseline:
//  * per-step sync is raw "s_waitcnt lgkmcnt(0); s_barrier" -> out[] stores and
//    staging loads stay in flight across steps (no per-step vmcnt(0) drain).
//  * xw is block-staged: 16 timesteps (16KB) of this batch's xw rows are
//    pulled into a double-buffered LDS buffer via global_load_lds width=16
//    (2 issues/wave/block), ONE vmcnt(0) per 16 steps. Per-step x access is
//    4 broadcast ds_read_u16 -> zero global-load latency on the step path.
//  * x is added AFTER the MFMA chain (epilogue), same as baseline, so the
//    MFMA chain is gated only by the LDS h read.
template <int LAYER>
__global__ __launch_bounds__(512, 2) void recur(const _Float16* __restrict__ xw,
                                                const _Float16* __restrict__ bblob,
                                                const void* __restrict__ lenp,
                                                _Float16* __restrict__ out0,
                                                float* __restrict__ out1,
                                                float* __restrict__ hn) {
  const int b    = blockIdx.x;             // batch
  const int tid  = threadIdx.x;
  const int w    = tid >> 6;               // wave 0..7
  const int lane = tid & 63;
  const int q = lane >> 4, l15 = lane & 15;
  const int len = read_len(lenp, b);

  // Whh B-fragments resident in VGPRs/AGPRs: [pp][kc], h tiles 2w+pp, t tiles 16+2w+pp
  f16x8 Bh[2][8], Bt[2][8];
#pragma unroll
  for (int pp = 0; pp < 2; pp++)
#pragma unroll
    for (int kc = 0; kc < 8; kc++) {
      Bh[pp][kc] = *(const f16x8*)(bblob + ((size_t)((2 * w + pp) * 8 + kc) * 64 + lane) * 8);
      Bt[pp][kc] = *(const f16x8*)(bblob + ((size_t)((16 + 2 * w + pp) * 8 + kc) * 64 + lane) * 8);
    }

  __shared__ __align__(16) _Float16 hbuf[2][DIM];        // ping-pong h (1 KB)
  __shared__ __align__(16) _Float16 xbuf[2][16][NCOL];   // 16-step xw blocks (32 KB)
  if (tid < DIM) hbuf[0][tid] = (_Float16)0.f;

  const int c0 = (2 * w) * 16 + l15;       // h-col of pp=0
  const int c1 = (2 * w + 1) * 16 + l15;   // h-col of pp=1
  const _Float16* xrow = xw + (size_t)b * NCOL;
  const size_t xstride = (size_t)BATCH * NCOL;

  // prologue: stage block 0 (steps 0..15) into xbuf[0]; wave w stages rows 2w,2w+1
  gload_lds_row(xrow + (size_t)(2 * w)     * xstride + lane * 8, &xbuf[0][2 * w][0]);
  gload_lds_row(xrow + (size_t)(2 * w + 1) * xstride + lane * 8, &xbuf[0][2 * w + 1][0]);
  asm volatile("s_waitcnt vmcnt(0)" ::: "memory");
  __syncthreads();

  float h0 = 0.f, h1 = 0.f;                // running h for cols c0, c1 (dup across q)
  const float K1 = 1.442695040888963f, K2 = 2.885390081777927f;

  for (int tb = 0; tb < T_STEPS / 16; ++tb) {
    const int buf = tb & 1;
    // issue staging for the NEXT block immediately; it flies under 16 steps
    // of compute and is only waited on at the block-end vmcnt(0).
    if (tb + 1 < T_STEPS / 16) {
      const _Float16* gsrc = xrow + (size_t)((tb + 1) * 16) * xstride;
      gload_lds_row(gsrc + (size_t)(2 * w)     * xstride + lane * 8, &xbuf[1 - buf][2 * w][0]);
      gload_lds_row(gsrc + (size_t)(2 * w + 1) * xstride + lane * 8, &xbuf[1 - buf][2 * w + 1][0]);
    }
#pragma unroll
    for (int ts = 0; ts < 16; ++ts) {
      const int t = tb * 16 + ts;
      const int p = ts & 1;                // tb*16 is even, so (t&1)==(ts&1)
      // x from LDS (broadcast reads; consumed only in the epilogue)
      const _Float16* xr = &xbuf[buf][ts][0];
      const float xh0 = (float)xr[c0],       xh1 = (float)xr[c1];
      const float xt0 = (float)xr[c0 + 256], xt1 = (float)xr[c1 + 256];

      f32x4 a0 = {0.f, 0.f, 0.f, 0.f}, a1 = a0, a2 = a0, a3 = a0;
      const _Float16* hb = &hbuf[p][q * 8];
#pragma unroll
      for (int kc = 0; kc < 8; kc++) {
        f16x8 a = *(const f16x8*)(hb + kc * 32);   // broadcast within q-group
        a0 = __builtin_amdgcn_mfma_f32_16x16x32_f16(a, Bh[0][kc], a0, 0, 0, 0);
        a1 = __builtin_amdgcn_mfma_f32_16x16x32_f16(a, Bh[1][kc], a1, 0, 0, 0);
        a2 = __builtin_amdgcn_mfma_f32_16x16x32_f16(a, Bt[0][kc], a2, 0, 0, 0);
        a3 = __builtin_amdgcn_mfma_f32_16x16x32_f16(a, Bt[1][kc], a3, 0, 0, 0);
      }
      const bool live = t < len;
      {
        float ph = a0[0] + xh0, pt = a2[0] + xt0;
        float phc = fminf(fmaxf(ph, -20.f), 20.f);
        float e1 = __builtin_amdgcn_exp2f(-K2 * phc);
        float e2 = __builtin_amdgcn_exp2f(-K1 * pt);
        float u1 = 1.f + e1;
        float rr = __builtin_amdgcn_rcpf(u1 * (1.f + e2));
        float ttg = (1.f - e1) * rr;
        float tg  = u1 * rr;
        float cg = 0.5f + tg * (0.250905f + tg * (-0.00432f + tg * (-0.015525f)));
        float s = ttg + h0 * cg;
        h0 = live ? s : h0;
      }
      {
        float ph = a1[0] + xh1, pt = a3[0] + xt1;
        float phc = fminf(fmaxf(ph, -20.f), 20.f);
        float e1 = __builtin_amdgcn_exp2f(-K2 * phc);
        float e2 = __builtin_amdgcn_exp2f(-K1 * pt);
        float u1 = 1.f + e1;
        float rr = __builtin_amdgcn_rcpf(u1 * (1.f + e2));
        float ttg = (1.f - e1) * rr;
        float tg  = u1 * rr;
        float cg = 0.5f + tg * (0.250905f + tg * (-0.00432f + tg * (-0.015525f)));
        float s = ttg + h1 * cg;
        h1 = live ? s : h1;
      }
      _Float16 s0 = (_Float16)h0, s1 = (_Float16)h1;
      if (q == 0) {                           // 16 lanes publish + store
        hbuf[1 - p][c0] = s0;
        hbuf[1 - p][c1] = s1;
        size_t o = ((size_t)t * BATCH + b) * DIM;
        if (LAYER == 0) { out0[o + c0] = s0; out0[o + c1] = s1; }
        else            { out1[o + c0] = h0; out1[o + c1] = h1; }
      }
      if (ts == 15) {
        // block boundary: next block's staging (issued 16 steps ago) must have
        // landed in LDS. Stores also drain here -- once per 16 steps.
        asm volatile("s_waitcnt vmcnt(0) lgkmcnt(0)\n\ts_barrier" ::: "memory");
      } else {
        // order ONLY the LDS h publish; global loads/stores stay in flight
        asm volatile("s_waitcnt lgkmcnt(0)\n\ts_barrier" ::: "memory");
      }
    }
  }

  if (q == 0) {
    hn[LAYER * (BATCH * DIM) + b * DIM + c0] = h0;
    hn[LAYER * (BATCH * DIM) + b * DIM + c1] = h1;
  }
}

extern "C" void kernel_launch(void* const* d_in, const int* in_sizes, int n_in,
                              void* d_out, int out_size, void* d_ws, size_t ws_size,
                              hipStream_t stream) {
  const float* input_ = (const float*)d_in[0];
  const void*  lenp   = d_in[1];
  const float* Wih0   = (const float*)d_in[2];
  const float* Whh0   = (const float*)d_in[3];
  const float* b0     = (const float*)d_in[4];
  const float* Wih1   = (const float*)d_in[5];
  const float* Whh1   = (const float*)d_in[6];
  const float* b1     = (const float*)d_in[7];
  float* out = (float*)d_out;
  char*  ws  = (char*)d_ws;

  _Float16* XW    = (_Float16*)(ws + XW_OFF);
  _Float16* Abuf  = (_Float16*)(ws + A_OFF);
  _Float16* blobs = (_Float16*)(ws + BLOB_OFF);   // [Wih0, Wih1, Whh0, Whh1]
  float* hn = out + M_ROWS * DIM;                 // d_out tail: h_n [2][32][256]

  cvt_f32_to_f16<<<16384, 256, 0, stream>>>(input_, Abuf, (int)(M_ROWS * DIM / 4));
  prep_blobs4<<<2048, 256, 0, stream>>>(Wih0, Wih1, Whh0, Whh1, blobs);
  gemm_xw<<<2048, 256, 0, stream>>>(Abuf, blobs + 0 * BLOB_ELT, b0, XW);
  recur<0><<<BATCH, 512, 0, stream>>>(XW, blobs + 2 * BLOB_ELT, lenp, Abuf, nullptr, hn);
  gemm_xw<<<2048, 256, 0, stream>>>(Abuf, blobs + 1 * BLOB_ELT, b1, XW);
  recur<1><<<BATCH, 512, 0, stream>>>(XW, blobs + 3 * BLOB_ELT, lenp, nullptr, out, hn);
}